// Round 1
// baseline (656.105 us; speedup 1.0000x reference)
//
#include <hip/hip_runtime.h>
#include <stdint.h>

#define NB   4
#define SEQ  4096
#define DIM  256
#define NROW (NB*SEQ)   // 16384

using bf16x8   = __attribute__((ext_vector_type(8))) __bf16;
using f32x4    = __attribute__((ext_vector_type(4))) float;
using u32x4    = __attribute__((ext_vector_type(4))) unsigned int;
using ushort4t = __attribute__((ext_vector_type(4))) unsigned short;

__device__ __forceinline__ unsigned f2bf(float f){
    unsigned u = __builtin_bit_cast(unsigned, f);
    return (u + 0x7fffu + ((u >> 16) & 1u)) >> 16;   // RNE to bf16 bits
}
__device__ __forceinline__ float bf2f(unsigned b){
    return __builtin_bit_cast(float, b << 16);
}

#define MFMA(a,b,c) __builtin_amdgcn_mfma_f32_16x16x32_bf16((a),(b),(c),0,0,0)

// ---------------------------------------------------------------------------
// Kernel 1: W[k][n] fp32 -> transposed split Wt_hi/Wt_lo[n][k] bf16
// ---------------------------------------------------------------------------
__global__ __launch_bounds__(256) void convert_w_kernel(
    const float* __restrict__ Wq, const float* __restrict__ Wk,
    const float* __restrict__ Wv,
    unsigned short* __restrict__ WtHi, unsigned short* __restrict__ WtLo)
{
    int mat = blockIdx.y;
    const float* W = (mat == 0) ? Wq : (mat == 1 ? Wk : Wv);
    int id = blockIdx.x * 256 + threadIdx.x;     // 0..65535
    int k = id >> 8, n = id & 255;
    float v = W[id];                              // == W[k*256+n], coalesced
    unsigned hi = f2bf(v);
    unsigned lo = f2bf(v - bf2f(hi));
    int o = mat * 65536 + n * 256 + k;            // transposed
    WtHi[o] = (unsigned short)hi;
    WtLo[o] = (unsigned short)lo;
}

// ---------------------------------------------------------------------------
// Kernel 2: fused QKV projection.  C = x@W + b via split bf16 MFMA
//   (xhi*Whi + xhi*Wlo + xlo*Whi).  Writes Qhi/Qlo/Khi/Klo row-major
//   [16384][256] bf16 and V transposed Vt[b][d][s] bf16.
// Block: 256 thr (4 waves), wave owns 16 rows. grid (256 mtiles, 2 nhalves).
// ---------------------------------------------------------------------------
__global__ __launch_bounds__(256) void proj_kernel(
    const float* __restrict__ x,
    const unsigned short* __restrict__ WtHi, const unsigned short* __restrict__ WtLo,
    const float* __restrict__ bq, const float* __restrict__ bk,
    const float* __restrict__ bv,
    unsigned short* __restrict__ Qhi, unsigned short* __restrict__ Qlo,
    unsigned short* __restrict__ Khi, unsigned short* __restrict__ Klo,
    unsigned short* __restrict__ Vt)
{
    const int tid = threadIdx.x, lane = tid & 63, wid = tid >> 6;
    const int g = lane >> 4, q16 = lane & 15;
    const int mbase = blockIdx.x * 64 + wid * 16;
    const int nh = blockIdx.y;

    f32x4 acc[3][8];
    #pragma unroll
    for (int m = 0; m < 3; m++)
        #pragma unroll
        for (int n = 0; n < 8; n++) acc[m][n] = f32x4{0.f, 0.f, 0.f, 0.f};

    const float* xr = x + (mbase + q16) * DIM;

    for (int kc = 0; kc < 8; kc++) {
        // A-fragment: x row (l&15), k = kc*32 + 8g + j, split hi/lo on the fly
        const float* p = xr + kc * 32 + 8 * g;
        f32x4 va = *(const f32x4*)p;
        f32x4 vb = *(const f32x4*)(p + 4);
        float fv[8] = {va[0], va[1], va[2], va[3], vb[0], vb[1], vb[2], vb[3]};
        unsigned hw[4], lw[4];
        #pragma unroll
        for (int i = 0; i < 4; i++) {
            unsigned h0 = f2bf(fv[2*i]),              h1 = f2bf(fv[2*i+1]);
            unsigned l0 = f2bf(fv[2*i]   - bf2f(h0)), l1 = f2bf(fv[2*i+1] - bf2f(h1));
            hw[i] = h0 | (h1 << 16);
            lw[i] = l0 | (l1 << 16);
        }
        bf16x8 ahi = __builtin_bit_cast(bf16x8, u32x4{hw[0], hw[1], hw[2], hw[3]});
        bf16x8 alo = __builtin_bit_cast(bf16x8, u32x4{lw[0], lw[1], lw[2], lw[3]});

        #pragma unroll
        for (int mat = 0; mat < 3; mat++) {
            #pragma unroll
            for (int nt = 0; nt < 8; nt++) {
                int ncol = nh * 128 + nt * 16 + q16;
                int off  = mat * 65536 + ncol * 256 + kc * 32 + 8 * g;
                bf16x8 bh = *(const bf16x8*)(WtHi + off);
                bf16x8 bl = *(const bf16x8*)(WtLo + off);
                acc[mat][nt] = MFMA(ahi, bh, acc[mat][nt]);
                acc[mat][nt] = MFMA(ahi, bl, acc[mat][nt]);
                acc[mat][nt] = MFMA(alo, bh, acc[mat][nt]);
            }
        }
    }

    // Epilogue: D layout row=(l>>4)*4+r, col=l&15
    #pragma unroll
    for (int nt = 0; nt < 8; nt++) {
        int ncol = nh * 128 + nt * 16 + q16;
        {   // Q -> hi/lo split
            float bb = bq[ncol];
            f32x4 c = acc[0][nt];
            #pragma unroll
            for (int r = 0; r < 4; r++) {
                float v = c[r] + bb;
                unsigned hi = f2bf(v), lo = f2bf(v - bf2f(hi));
                int mrow = mbase + 4 * g + r;
                Qhi[mrow * DIM + ncol] = (unsigned short)hi;
                Qlo[mrow * DIM + ncol] = (unsigned short)lo;
            }
        }
        {   // K -> hi/lo split
            float bb = bk[ncol];
            f32x4 c = acc[1][nt];
            #pragma unroll
            for (int r = 0; r < 4; r++) {
                float v = c[r] + bb;
                unsigned hi = f2bf(v), lo = f2bf(v - bf2f(hi));
                int mrow = mbase + 4 * g + r;
                Khi[mrow * DIM + ncol] = (unsigned short)hi;
                Klo[mrow * DIM + ncol] = (unsigned short)lo;
            }
        }
        {   // V -> transposed bf16 Vt[b][d][s]; 4 consecutive s -> 8B store
            float bb = bv[ncol];
            f32x4 c = acc[2][nt];
            ushort4t pk;
            #pragma unroll
            for (int r = 0; r < 4; r++) pk[r] = (unsigned short)f2bf(c[r] + bb);
            int m0 = mbase + 4 * g;
            int bat = m0 >> 12, s0 = m0 & 4095;
            *(ushort4t*)(Vt + (bat * DIM + ncol) * SEQ + s0) = pk;
        }
    }
}

// ---------------------------------------------------------------------------
// Kernel 3: flash attention, swapped-QK^T, split-precision scores.
// Block: 4 waves x 16 q-rows = 64 q rows. grid (64 qtiles, 4 batches).
// kv chunk = 32 (matches MFMA K for PV). K hi/lo + Vt staged in LDS.
// ---------------------------------------------------------------------------
__global__ __launch_bounds__(256) void flash_kernel(
    const unsigned short* __restrict__ Qhi, const unsigned short* __restrict__ Qlo,
    const unsigned short* __restrict__ Khi, const unsigned short* __restrict__ Klo,
    const unsigned short* __restrict__ Vt,
    const float* __restrict__ x, float* __restrict__ out)
{
    __shared__ __align__(16) unsigned short khi_lds[32 * 264];  // +8 elem pad
    __shared__ __align__(16) unsigned short klo_lds[32 * 264];
    __shared__ __align__(16) unsigned short v_lds[256 * 40];    // +8 elem pad

    const int tid = threadIdx.x, lane = tid & 63, wid = tid >> 6;
    const int g = lane >> 4, q16 = lane & 15;
    const int b = blockIdx.y;
    const int grow = b * SEQ + blockIdx.x * 64 + wid * 16; // wave's first q row

    // Q fragments (hi/lo) for this wave's 16 rows, held in registers
    bf16x8 qh[8], ql[8];
    {
        const unsigned short* ph = Qhi + (grow + q16) * DIM + 8 * g;
        const unsigned short* pl = Qlo + (grow + q16) * DIM + 8 * g;
        #pragma unroll
        for (int kc = 0; kc < 8; kc++) {
            qh[kc] = *(const bf16x8*)(ph + kc * 32);
            ql[kc] = *(const bf16x8*)(pl + kc * 32);
        }
    }

    f32x4 o[16];
    #pragma unroll
    for (int i = 0; i < 16; i++) o[i] = f32x4{0.f, 0.f, 0.f, 0.f};
    float m_run = -3.0e38f, l_run = 0.f;

    // P-redistribution shuffle sources (see derivation in journal):
    // lane needs P[q=l&15][kv=8g+j]; j<4 from lane sl0, j>=4 from sl1,
    // both from score tile ts = g>>1.
    const int  sl0 = q16 | (((2 * g    ) & 3) << 4);
    const int  sl1 = q16 | (((2 * g + 1) & 3) << 4);
    const bool thi = (g >> 1) != 0;

    for (int c = 0; c < 128; c++) {
        const int kv0 = c * 32;
        __syncthreads();
        // ---- stage K hi/lo (32x256) and Vt (256x32) chunk into LDS ----
        #pragma unroll
        for (int i = 0; i < 4; i++) {
            int idx = tid + i * 256;
            int row = idx >> 5, cc = idx & 31;
            int gsrc = (b * SEQ + kv0 + row) * DIM + cc * 8;
            *(bf16x8*)(khi_lds + row * 264 + cc * 8) = *(const bf16x8*)(Khi + gsrc);
            *(bf16x8*)(klo_lds + row * 264 + cc * 8) = *(const bf16x8*)(Klo + gsrc);
            int vrow = idx >> 2, vcc = idx & 3;
            *(bf16x8*)(v_lds + vrow * 40 + vcc * 8) =
                *(const bf16x8*)(Vt + (b * DIM + vrow) * SEQ + kv0 + vcc * 8);
        }
        __syncthreads();

        // ---- scores: S^T tiles via mfma(A=K, B=Q); 4 indep chains ----
        f32x4 sA0{0.f,0.f,0.f,0.f}, sA1{0.f,0.f,0.f,0.f};
        f32x4 sB0{0.f,0.f,0.f,0.f}, sB1{0.f,0.f,0.f,0.f};
        #pragma unroll
        for (int kc = 0; kc < 8; kc++) {
            const int ob = q16 * 264 + kc * 32 + 8 * g;
            bf16x8 kh0 = *(const bf16x8*)(khi_lds + ob);
            bf16x8 kl0 = *(const bf16x8*)(klo_lds + ob);
            bf16x8 kh1 = *(const bf16x8*)(khi_lds + ob + 16 * 264);
            bf16x8 kl1 = *(const bf16x8*)(klo_lds + ob + 16 * 264);
            if ((kc & 1) == 0) {
                sA0 = MFMA(kh0, qh[kc], sA0);  sA1 = MFMA(kh1, qh[kc], sA1);
                sA0 = MFMA(kh0, ql[kc], sA0);  sA1 = MFMA(kh1, ql[kc], sA1);
                sA0 = MFMA(kl0, qh[kc], sA0);  sA1 = MFMA(kl1, qh[kc], sA1);
            } else {
                sB0 = MFMA(kh0, qh[kc], sB0);  sB1 = MFMA(kh1, qh[kc], sB1);
                sB0 = MFMA(kh0, ql[kc], sB0);  sB1 = MFMA(kh1, ql[kc], sB1);
                sB0 = MFMA(kl0, qh[kc], sB0);  sB1 = MFMA(kl1, qh[kc], sB1);
            }
        }
        f32x4 s0 = sA0 + sB0, s1 = sA1 + sB1;
        // lane holds S[q=q16][kv = 16t + 4g + r] in s{t}[r]

        // ---- online softmax (row = q16; reduce across lane^16, lane^32) ----
        float pm = fmaxf(fmaxf(fmaxf(s0[0], s0[1]), fmaxf(s0[2], s0[3])),
                         fmaxf(fmaxf(s1[0], s1[1]), fmaxf(s1[2], s1[3])));
        pm = fmaxf(pm, __shfl_xor(pm, 16, 64));
        pm = fmaxf(pm, __shfl_xor(pm, 32, 64));
        float m_new = fmaxf(m_run, pm);
        float p0 = __expf(s0[0] - m_new), p1 = __expf(s0[1] - m_new);
        float p2 = __expf(s0[2] - m_new), p3 = __expf(s0[3] - m_new);
        float p4 = __expf(s1[0] - m_new), p5 = __expf(s1[1] - m_new);
        float p6 = __expf(s1[2] - m_new), p7 = __expf(s1[3] - m_new);
        float psum = ((p0 + p1) + (p2 + p3)) + ((p4 + p5) + (p6 + p7));
        psum += __shfl_xor(psum, 16, 64);
        psum += __shfl_xor(psum, 32, 64);
        float scale = __expf(m_run - m_new);
        l_run = l_run * scale + psum;
        m_run = m_new;

        // ---- redistribute P into A-fragment layout via shuffles ----
        unsigned w00 = f2bf(p0) | (f2bf(p1) << 16);
        unsigned w01 = f2bf(p2) | (f2bf(p3) << 16);
        unsigned w10 = f2bf(p4) | (f2bf(p5) << 16);
        unsigned w11 = f2bf(p6) | (f2bf(p7) << 16);
        unsigned a0 = (unsigned)__shfl((int)w00, sl0, 64);
        unsigned a1 = (unsigned)__shfl((int)w01, sl0, 64);
        unsigned a2 = (unsigned)__shfl((int)w10, sl0, 64);
        unsigned a3 = (unsigned)__shfl((int)w11, sl0, 64);
        unsigned b0 = (unsigned)__shfl((int)w00, sl1, 64);
        unsigned b1 = (unsigned)__shfl((int)w01, sl1, 64);
        unsigned b2 = (unsigned)__shfl((int)w10, sl1, 64);
        unsigned b3 = (unsigned)__shfl((int)w11, sl1, 64);
        u32x4 pw;
        pw[0] = thi ? a2 : a0;
        pw[1] = thi ? a3 : a1;
        pw[2] = thi ? b2 : b0;
        pw[3] = thi ? b3 : b1;
        bf16x8 pf = __builtin_bit_cast(bf16x8, pw);

        // ---- rescale O (per-reg q row = 4g+r) and accumulate P·V ----
        float sc0 = __shfl(scale, 4 * g + 0, 64);
        float sc1 = __shfl(scale, 4 * g + 1, 64);
        float sc2 = __shfl(scale, 4 * g + 2, 64);
        float sc3 = __shfl(scale, 4 * g + 3, 64);
        #pragma unroll
        for (int dt = 0; dt < 16; dt++) {
            bf16x8 vf = *(const bf16x8*)(v_lds + (dt * 16 + q16) * 40 + 8 * g);
            f32x4 oo = o[dt];
            oo[0] *= sc0; oo[1] *= sc1; oo[2] *= sc2; oo[3] *= sc3;
            o[dt] = MFMA(pf, vf, oo);
        }
    }

    // ---- epilogue: divide by l, add residual, store fp32 ----
    float rl = 1.0f / l_run;
    float li0 = __shfl(rl, 4 * g + 0, 64);
    float li1 = __shfl(rl, 4 * g + 1, 64);
    float li2 = __shfl(rl, 4 * g + 2, 64);
    float li3 = __shfl(rl, 4 * g + 3, 64);
    #pragma unroll
    for (int dt = 0; dt < 16; dt++) {
        int col = dt * 16 + q16;
        #pragma unroll
        for (int r = 0; r < 4; r++) {
            int mrow = grow + 4 * g + r;
            float lv = (r == 0) ? li0 : (r == 1) ? li1 : (r == 2) ? li2 : li3;
            out[mrow * DIM + col] = o[dt][r] * lv + x[mrow * DIM + col];
        }
    }
}

// ---------------------------------------------------------------------------
extern "C" void kernel_launch(void* const* d_in, const int* in_sizes, int n_in,
                              void* d_out, int out_size, void* d_ws, size_t ws_size,
                              hipStream_t stream)
{
    const float* x  = (const float*)d_in[0];
    const float* Wq = (const float*)d_in[1];
    const float* bq = (const float*)d_in[2];
    const float* Wk = (const float*)d_in[3];
    const float* bk = (const float*)d_in[4];
    const float* Wv = (const float*)d_in[5];
    const float* bv = (const float*)d_in[6];
    float* out = (float*)d_out;

    unsigned char* ws = (unsigned char*)d_ws;
    unsigned short* Qhi  = (unsigned short*)(ws);
    unsigned short* Qlo  = (unsigned short*)(ws +  8388608);
    unsigned short* Khi  = (unsigned short*)(ws + 16777216);
    unsigned short* Klo  = (unsigned short*)(ws + 25165824);
    unsigned short* Vt   = (unsigned short*)(ws + 33554432);
    unsigned short* WtHi = (unsigned short*)(ws + 41943040);
    unsigned short* WtLo = (unsigned short*)(ws + 42336256);
    // total ws use: 42,729,472 bytes

    convert_w_kernel<<<dim3(256, 3), 256, 0, stream>>>(Wq, Wk, Wv, WtHi, WtLo);
    proj_kernel<<<dim3(256, 2), 256, 0, stream>>>(x, WtHi, WtLo, bq, bk, bv,
                                                  Qhi, Qlo, Khi, Klo, Vt);
    flash_kernel<<<dim3(64, 4), 256, 0, stream>>>(Qhi, Qlo, Khi, Klo, Vt, x, out);
}

// Round 2
// 277.690 us; speedup vs baseline: 2.3627x; 2.3627x over previous
//
#include <hip/hip_runtime.h>
#include <stdint.h>

#define NB   4
#define SEQ  4096
#define DIM  256
#define NROW (NB*SEQ)   // 16384

using bf16x8   = __attribute__((ext_vector_type(8))) __bf16;
using f32x4    = __attribute__((ext_vector_type(4))) float;
using u32x4    = __attribute__((ext_vector_type(4))) unsigned int;
using ushort4t = __attribute__((ext_vector_type(4))) unsigned short;

__device__ __forceinline__ unsigned f2bf(float f){
    unsigned u = __builtin_bit_cast(unsigned, f);
    return (u + 0x7fffu + ((u >> 16) & 1u)) >> 16;   // RNE to bf16 bits
}
__device__ __forceinline__ float bf2f(unsigned b){
    return __builtin_bit_cast(float, b << 16);
}

#define MFMA(a,b,c) __builtin_amdgcn_mfma_f32_16x16x32_bf16((a),(b),(c),0,0,0)

// async global -> LDS, 16 B per lane. LDS dest = wave-uniform base + lane*16.
__device__ __forceinline__ void gld16(const unsigned short* g, unsigned short* l){
    __builtin_amdgcn_global_load_lds(
        (const __attribute__((address_space(1))) void*)g,
        (__attribute__((address_space(3))) void*)l, 16, 0, 0);
}

// ---------------------------------------------------------------------------
// Kernel 1: W[k][n] fp32 -> transposed split Wt_hi/Wt_lo[n][k] bf16
// ---------------------------------------------------------------------------
__global__ __launch_bounds__(256) void convert_w_kernel(
    const float* __restrict__ Wq, const float* __restrict__ Wk,
    const float* __restrict__ Wv,
    unsigned short* __restrict__ WtHi, unsigned short* __restrict__ WtLo)
{
    int mat = blockIdx.y;
    const float* W = (mat == 0) ? Wq : (mat == 1 ? Wk : Wv);
    int id = blockIdx.x * 256 + threadIdx.x;     // 0..65535
    int k = id >> 8, n = id & 255;
    float v = W[id];
    unsigned hi = f2bf(v);
    unsigned lo = f2bf(v - bf2f(hi));
    int o = mat * 65536 + n * 256 + k;            // transposed
    WtHi[o] = (unsigned short)hi;
    WtLo[o] = (unsigned short)lo;
}

// ---------------------------------------------------------------------------
// Kernel 2: fused QKV projection (unchanged from R1 — known good, ~80us,
// optimize next round once flash stops dominating).
// ---------------------------------------------------------------------------
__global__ __launch_bounds__(256) void proj_kernel(
    const float* __restrict__ x,
    const unsigned short* __restrict__ WtHi, const unsigned short* __restrict__ WtLo,
    const float* __restrict__ bq, const float* __restrict__ bk,
    const float* __restrict__ bv,
    unsigned short* __restrict__ Qhi, unsigned short* __restrict__ Qlo,
    unsigned short* __restrict__ Khi, unsigned short* __restrict__ Klo,
    unsigned short* __restrict__ Vt)
{
    const int tid = threadIdx.x, lane = tid & 63, wid = tid >> 6;
    const int g = lane >> 4, q16 = lane & 15;
    const int mbase = blockIdx.x * 64 + wid * 16;
    const int nh = blockIdx.y;

    f32x4 acc[3][8];
    #pragma unroll
    for (int m = 0; m < 3; m++)
        #pragma unroll
        for (int n = 0; n < 8; n++) acc[m][n] = f32x4{0.f, 0.f, 0.f, 0.f};

    const float* xr = x + (mbase + q16) * DIM;

    for (int kc = 0; kc < 8; kc++) {
        const float* p = xr + kc * 32 + 8 * g;
        f32x4 va = *(const f32x4*)p;
        f32x4 vb = *(const f32x4*)(p + 4);
        float fv[8] = {va[0], va[1], va[2], va[3], vb[0], vb[1], vb[2], vb[3]};
        unsigned hw[4], lw[4];
        #pragma unroll
        for (int i = 0; i < 4; i++) {
            unsigned h0 = f2bf(fv[2*i]),              h1 = f2bf(fv[2*i+1]);
            unsigned l0 = f2bf(fv[2*i]   - bf2f(h0)), l1 = f2bf(fv[2*i+1] - bf2f(h1));
            hw[i] = h0 | (h1 << 16);
            lw[i] = l0 | (l1 << 16);
        }
        bf16x8 ahi = __builtin_bit_cast(bf16x8, u32x4{hw[0], hw[1], hw[2], hw[3]});
        bf16x8 alo = __builtin_bit_cast(bf16x8, u32x4{lw[0], lw[1], lw[2], lw[3]});

        #pragma unroll
        for (int mat = 0; mat < 3; mat++) {
            #pragma unroll
            for (int nt = 0; nt < 8; nt++) {
                int ncol = nh * 128 + nt * 16 + q16;
                int off  = mat * 65536 + ncol * 256 + kc * 32 + 8 * g;
                bf16x8 bh = *(const bf16x8*)(WtHi + off);
                bf16x8 bl = *(const bf16x8*)(WtLo + off);
                acc[mat][nt] = MFMA(ahi, bh, acc[mat][nt]);
                acc[mat][nt] = MFMA(ahi, bl, acc[mat][nt]);
                acc[mat][nt] = MFMA(alo, bh, acc[mat][nt]);
            }
        }
    }

    #pragma unroll
    for (int nt = 0; nt < 8; nt++) {
        int ncol = nh * 128 + nt * 16 + q16;
        {
            float bb = bq[ncol];
            f32x4 c = acc[0][nt];
            #pragma unroll
            for (int r = 0; r < 4; r++) {
                float v = c[r] + bb;
                unsigned hi = f2bf(v), lo = f2bf(v - bf2f(hi));
                int mrow = mbase + 4 * g + r;
                Qhi[mrow * DIM + ncol] = (unsigned short)hi;
                Qlo[mrow * DIM + ncol] = (unsigned short)lo;
            }
        }
        {
            float bb = bk[ncol];
            f32x4 c = acc[1][nt];
            #pragma unroll
            for (int r = 0; r < 4; r++) {
                float v = c[r] + bb;
                unsigned hi = f2bf(v), lo = f2bf(v - bf2f(hi));
                int mrow = mbase + 4 * g + r;
                Khi[mrow * DIM + ncol] = (unsigned short)hi;
                Klo[mrow * DIM + ncol] = (unsigned short)lo;
            }
        }
        {
            float bb = bv[ncol];
            f32x4 c = acc[2][nt];
            ushort4t pk;
            #pragma unroll
            for (int r = 0; r < 4; r++) pk[r] = (unsigned short)f2bf(c[r] + bb);
            int m0 = mbase + 4 * g;
            int bat = m0 >> 12, s0 = m0 & 4095;
            *(ushort4t*)(Vt + (bat * DIM + ncol) * SEQ + s0) = pk;
        }
    }
}

// ---------------------------------------------------------------------------
// Kernel 3: flash attention. 8 waves x 16 q-rows = 128 rows/block.
// grid (128 qtiles, 2 kv-splits). Per split: 2048 kv = 64 chunks of 32.
// Double-buffered async staging (global_load_lds, source-side XOR swizzle).
// Writes UNNORMALIZED partial O + (m,l); combine kernel merges splits.
// LDS: K hi/lo [2][32][256] + V [2][256][32] = 96 KB.
// ---------------------------------------------------------------------------
#define KHI_O 0
#define KLO_O 16384
#define VLD_O 32768

__global__ __launch_bounds__(512, 2) void flash_kernel(
    const unsigned short* __restrict__ Qhi, const unsigned short* __restrict__ Qlo,
    const unsigned short* __restrict__ Khi, const unsigned short* __restrict__ Klo,
    const unsigned short* __restrict__ Vt,
    float* __restrict__ o0, unsigned short* __restrict__ o1,
    float2* __restrict__ ml0, float2* __restrict__ ml1)
{
    __shared__ __align__(16) unsigned short smem[49152];   // 96 KB

    const int tid = threadIdx.x, lane = tid & 63, wid = tid >> 6;
    const int g = lane >> 4, q16 = lane & 15;
    const int qrow = blockIdx.x * 128 + wid * 16;   // wave's first global q row
    const int b = qrow >> 12;                       // batch
    const int split = blockIdx.y;
    const int kvbase = split * 2048;                // within-batch kv start
    const int bofs = b * SEQ;                       // K row base
    const int vofs = b * DIM;                       // Vt row base

    // --- Q fragments (hi/lo) in registers ---
    bf16x8 qh[8], ql[8];
    {
        const unsigned short* ph = Qhi + (size_t)(qrow + q16) * DIM + 8 * g;
        const unsigned short* pl = Qlo + (size_t)(qrow + q16) * DIM + 8 * g;
        #pragma unroll
        for (int kc = 0; kc < 8; kc++) {
            qh[kc] = *(const bf16x8*)(ph + kc * 32);
            ql[kc] = *(const bf16x8*)(pl + kc * 32);
        }
    }

    f32x4 o[16];
    #pragma unroll
    for (int i = 0; i < 16; i++) o[i] = f32x4{0.f, 0.f, 0.f, 0.f};
    float m_run = -3.0e38f, l_run = 0.f;

    // P-shuffle sources (same derivation as R1)
    const int  sl0 = q16 | (((2 * g    ) & 3) << 4);
    const int  sl1 = q16 | (((2 * g + 1) & 3) << 4);
    const bool thi = (g >> 1) != 0;
    const int  ksw  = q16 & 7;
    const int  vswz = (g ^ ((q16 >> 1) & 3)) * 8;

    // ---- staging: 6 x global_load_lds per wave per chunk ----
    // K: instr t=wid*2+i covers rows 2t,2t+1; lane: row 2t+(l>>5), 16B chunk l&31,
    //    source chunk pre-XOR'd with (row&7) -> LDS holds swizzled layout.
    // V: instr t covers d rows 16t..16t+15; lane: d=16t+(l>>2), chunk l&3,
    //    source chunk XOR'd with ((d>>1)&3).
    auto stage = [&](int chunk, int tbf) {
        const int kv0 = kvbase + chunk * 32;
        #pragma unroll
        for (int i = 0; i < 2; i++) {
            const int t  = wid * 2 + i;
            const int r  = 2 * t + (lane >> 5);
            const int sc = (lane & 31) ^ (r & 7);
            const size_t go = (size_t)(bofs + kv0 + r) * DIM + sc * 8;
            gld16(Khi + go, &smem[KHI_O + tbf * 8192 + t * 512]);
            gld16(Klo + go, &smem[KLO_O + tbf * 8192 + t * 512]);
            const int d   = t * 16 + (lane >> 2);
            const int vsc = (lane & 3) ^ ((d >> 1) & 3);
            gld16(Vt + (size_t)(vofs + d) * SEQ + kv0 + vsc * 8,
                  &smem[VLD_O + tbf * 8192 + t * 512]);
        }
    };

    stage(0, 0);
    __syncthreads();   // drains vmcnt before barrier

    for (int c = 0; c < 64; c++) {
        const int bf = c & 1;
        if (c + 1 < 64) stage(c + 1, bf ^ 1);   // async prefetch into other buffer

        // ---- scores: S^T tiles via mfma(A=K, B=Q); swizzled LDS reads ----
        const unsigned short* ph = smem + KHI_O + bf * 8192;
        const unsigned short* pl = smem + KLO_O + bf * 8192;
        f32x4 sA0{0.f,0.f,0.f,0.f}, sA1{0.f,0.f,0.f,0.f};
        f32x4 sB0{0.f,0.f,0.f,0.f}, sB1{0.f,0.f,0.f,0.f};
        __builtin_amdgcn_s_setprio(1);
        #pragma unroll
        for (int kc = 0; kc < 8; kc++) {
            const int off0 = q16 * 256 + (((kc * 4 + g) ^ ksw) * 8);
            bf16x8 kh0 = *(const bf16x8*)(ph + off0);
            bf16x8 kl0 = *(const bf16x8*)(pl + off0);
            bf16x8 kh1 = *(const bf16x8*)(ph + off0 + 4096);
            bf16x8 kl1 = *(const bf16x8*)(pl + off0 + 4096);
            if ((kc & 1) == 0) {
                sA0 = MFMA(kh0, qh[kc], sA0);  sA1 = MFMA(kh1, qh[kc], sA1);
                sA0 = MFMA(kh0, ql[kc], sA0);  sA1 = MFMA(kh1, ql[kc], sA1);
                sA0 = MFMA(kl0, qh[kc], sA0);  sA1 = MFMA(kl1, qh[kc], sA1);
            } else {
                sB0 = MFMA(kh0, qh[kc], sB0);  sB1 = MFMA(kh1, qh[kc], sB1);
                sB0 = MFMA(kh0, ql[kc], sB0);  sB1 = MFMA(kh1, ql[kc], sB1);
                sB0 = MFMA(kl0, qh[kc], sB0);  sB1 = MFMA(kl1, qh[kc], sB1);
            }
        }
        __builtin_amdgcn_s_setprio(0);
        f32x4 s0 = sA0 + sB0, s1 = sA1 + sB1;

        // ---- online softmax (row = q16) ----
        float pm = fmaxf(fmaxf(fmaxf(s0[0], s0[1]), fmaxf(s0[2], s0[3])),
                         fmaxf(fmaxf(s1[0], s1[1]), fmaxf(s1[2], s1[3])));
        pm = fmaxf(pm, __shfl_xor(pm, 16, 64));
        pm = fmaxf(pm, __shfl_xor(pm, 32, 64));
        float m_new = fmaxf(m_run, pm);
        float p0 = __expf(s0[0] - m_new), p1 = __expf(s0[1] - m_new);
        float p2 = __expf(s0[2] - m_new), p3 = __expf(s0[3] - m_new);
        float p4 = __expf(s1[0] - m_new), p5 = __expf(s1[1] - m_new);
        float p6 = __expf(s1[2] - m_new), p7 = __expf(s1[3] - m_new);
        float psum = ((p0 + p1) + (p2 + p3)) + ((p4 + p5) + (p6 + p7));
        psum += __shfl_xor(psum, 16, 64);
        psum += __shfl_xor(psum, 32, 64);
        float scale = __expf(m_run - m_new);
        l_run = l_run * scale + psum;
        m_run = m_new;

        // ---- redistribute P into A-fragment layout ----
        unsigned w00 = f2bf(p0) | (f2bf(p1) << 16);
        unsigned w01 = f2bf(p2) | (f2bf(p3) << 16);
        unsigned w10 = f2bf(p4) | (f2bf(p5) << 16);
        unsigned w11 = f2bf(p6) | (f2bf(p7) << 16);
        unsigned a0 = (unsigned)__shfl((int)w00, sl0, 64);
        unsigned a1 = (unsigned)__shfl((int)w01, sl0, 64);
        unsigned a2 = (unsigned)__shfl((int)w10, sl0, 64);
        unsigned a3 = (unsigned)__shfl((int)w11, sl0, 64);
        unsigned b0 = (unsigned)__shfl((int)w00, sl1, 64);
        unsigned b1 = (unsigned)__shfl((int)w01, sl1, 64);
        unsigned b2 = (unsigned)__shfl((int)w10, sl1, 64);
        unsigned b3 = (unsigned)__shfl((int)w11, sl1, 64);
        u32x4 pw;
        pw[0] = thi ? a2 : a0;
        pw[1] = thi ? a3 : a1;
        pw[2] = thi ? b2 : b0;
        pw[3] = thi ? b3 : b1;
        bf16x8 pf = __builtin_bit_cast(bf16x8, pw);

        // ---- rescale O and accumulate P.V (swizzled V reads) ----
        float sc0 = __shfl(scale, 4 * g + 0, 64);
        float sc1 = __shfl(scale, 4 * g + 1, 64);
        float sc2 = __shfl(scale, 4 * g + 2, 64);
        float sc3 = __shfl(scale, 4 * g + 3, 64);
        const unsigned short* pv = smem + VLD_O + bf * 8192;
        __builtin_amdgcn_s_setprio(1);
        #pragma unroll
        for (int dt = 0; dt < 16; dt++) {
            bf16x8 vf = *(const bf16x8*)(pv + dt * 512 + q16 * 32 + vswz);
            f32x4 oo = o[dt];
            oo[0] *= sc0; oo[1] *= sc1; oo[2] *= sc2; oo[3] *= sc3;
            o[dt] = MFMA(pf, vf, oo);
        }
        __builtin_amdgcn_s_setprio(0);

        __syncthreads();   // implicit vmcnt(0)+lgkmcnt(0): prefetch landed, buffers safe
    }

    // ---- epilogue: store UNNORMALIZED partial + (m,l) ----
    if (split == 0) {
        #pragma unroll
        for (int dt = 0; dt < 16; dt++) {
            int col = dt * 16 + q16;
            #pragma unroll
            for (int r = 0; r < 4; r++)
                o0[(size_t)(qrow + 4 * g + r) * DIM + col] = o[dt][r];
        }
        if (g == 0) ml0[qrow + q16] = float2{m_run, l_run};
    } else {
        #pragma unroll
        for (int dt = 0; dt < 16; dt++) {
            int col = dt * 16 + q16;
            #pragma unroll
            for (int r = 0; r < 4; r++)
                o1[(size_t)(qrow + 4 * g + r) * DIM + col] =
                    (unsigned short)f2bf(o[dt][r]);
        }
        if (g == 0) ml1[qrow + q16] = float2{m_run, l_run};
    }
}

// ---------------------------------------------------------------------------
// Kernel 4: merge the two kv-split partials + residual.
// out = (w0*o0 + w1*o1) / (w0*l0 + w1*l1) + x,  wi = exp(mi - max(m0,m1))
// ---------------------------------------------------------------------------
__global__ __launch_bounds__(256) void combine_kernel(
    const float* __restrict__ o0, const unsigned short* __restrict__ o1,
    const float2* __restrict__ ml0, const float2* __restrict__ ml1,
    const float* __restrict__ x, float* __restrict__ out)
{
    int row = blockIdx.x * 4 + (threadIdx.x >> 6);
    int c0  = (threadIdx.x & 63) * 4;
    float2 A = ml0[row], B = ml1[row];
    float M  = fmaxf(A.x, B.x);
    float w0 = __expf(A.x - M), w1 = __expf(B.x - M);
    float inv = 1.0f / (w0 * A.y + w1 * B.y);
    size_t base = (size_t)row * DIM + c0;
    f32x4    v0 = *(const f32x4*)(o0 + base);
    ushort4t u1 = *(const ushort4t*)(o1 + base);
    f32x4    xr = *(const f32x4*)(x + base);
    f32x4 res;
    #pragma unroll
    for (int j = 0; j < 4; j++)
        res[j] = (w0 * v0[j] + w1 * bf2f((unsigned)u1[j])) * inv + xr[j];
    *(f32x4*)(out + base) = res;
}

// ---------------------------------------------------------------------------
extern "C" void kernel_launch(void* const* d_in, const int* in_sizes, int n_in,
                              void* d_out, int out_size, void* d_ws, size_t ws_size,
                              hipStream_t stream)
{
    const float* x  = (const float*)d_in[0];
    const float* Wq = (const float*)d_in[1];
    const float* bq = (const float*)d_in[2];
    const float* Wk = (const float*)d_in[3];
    const float* bk = (const float*)d_in[4];
    const float* Wv = (const float*)d_in[5];
    const float* bv = (const float*)d_in[6];
    float* out = (float*)d_out;

    unsigned char* ws = (unsigned char*)d_ws;
    unsigned short* Qhi  = (unsigned short*)(ws);
    unsigned short* Qlo  = (unsigned short*)(ws +  8388608);
    unsigned short* Khi  = (unsigned short*)(ws + 16777216);
    unsigned short* Klo  = (unsigned short*)(ws + 25165824);
    unsigned short* Vt   = (unsigned short*)(ws + 33554432);
    unsigned short* WtHi = (unsigned short*)(ws + 41943040);
    unsigned short* WtLo = (unsigned short*)(ws + 42336256);
    unsigned short* O1   = (unsigned short*)(ws + 42729472);  // bf16 partial, split 1
    float2*         ML0  = (float2*)       (ws + 51118080);
    float2*         ML1  = (float2*)       (ws + 51249152);
    // total ws use: 51,380,224 bytes

    convert_w_kernel<<<dim3(256, 3), 256, 0, stream>>>(Wq, Wk, Wv, WtHi, WtLo);
    proj_kernel<<<dim3(256, 2), 256, 0, stream>>>(x, WtHi, WtLo, bq, bk, bv,
                                                  Qhi, Qlo, Khi, Klo, Vt);
    // split 0 partial (fp32) goes straight into d_out; combine rewrites in place.
    flash_kernel<<<dim3(128, 2), 512, 0, stream>>>(Qhi, Qlo, Khi, Klo, Vt,
                                                   out, O1, ML0, ML1);
    combine_kernel<<<4096, 256, 0, stream>>>(out, O1, ML0, ML1, x, out);
}

// Round 3
// 233.397 us; speedup vs baseline: 2.8111x; 1.1898x over previous
//
#include <hip/hip_runtime.h>
#include <stdint.h>

#define NB   4
#define SEQ  4096
#define DIM  256
#define NROW (NB*SEQ)   // 16384

using bf16x8   = __attribute__((ext_vector_type(8))) __bf16;
using f32x4    = __attribute__((ext_vector_type(4))) float;
using u32x4    = __attribute__((ext_vector_type(4))) unsigned int;
using i32x4    = __attribute__((ext_vector_type(4))) int;
using short4v  = __attribute__((ext_vector_type(4))) short;
using short8v  = __attribute__((ext_vector_type(8))) short;
using ushort4t = __attribute__((ext_vector_type(4))) unsigned short;

__device__ __forceinline__ unsigned f2bf(float f){
    unsigned u = __builtin_bit_cast(unsigned, f);
    return (u + 0x7fffu + ((u >> 16) & 1u)) >> 16;   // RNE to bf16 bits
}
__device__ __forceinline__ float bf2f(unsigned b){
    return __builtin_bit_cast(float, b << 16);
}

#define MFMA(a,b,c)  __builtin_amdgcn_mfma_f32_16x16x32_bf16((a),(b),(c),0,0,0)
#define MFMA8(a,b,c) __builtin_amdgcn_mfma_i32_16x16x64_i8((a),(b),(c),0,0,0)
#define MFMAP(a,b,c) __builtin_amdgcn_mfma_f32_16x16x16bf16_1k((a),(b),(c),0,0,0)

// async global -> LDS, 16 B per lane. LDS dest = wave-uniform base + lane*16.
__device__ __forceinline__ void gld16(const void* g, void* l){
    __builtin_amdgcn_global_load_lds(
        (const __attribute__((address_space(1))) void*)g,
        (__attribute__((address_space(3))) void*)l, 16, 0, 0);
}

// int8 duo quantization scale: values in [-7,7] -> int8 pair
#define QSCALE (127.0f/7.0f)
#define C0 ((7.0f/127.0f)*(7.0f/127.0f))
#define C1 (C0/254.0f)

// ---------------------------------------------------------------------------
// Kernel 1: W[k][n] fp32 -> transposed split Wt_hi/Wt_lo[n][k] bf16
// ---------------------------------------------------------------------------
__global__ __launch_bounds__(256) void convert_w_kernel(
    const float* __restrict__ Wq, const float* __restrict__ Wk,
    const float* __restrict__ Wv,
    unsigned short* __restrict__ WtHi, unsigned short* __restrict__ WtLo)
{
    int mat = blockIdx.y;
    const float* W = (mat == 0) ? Wq : (mat == 1 ? Wk : Wv);
    int id = blockIdx.x * 256 + threadIdx.x;     // 0..65535
    int k = id >> 8, n = id & 255;
    float v = W[id];
    unsigned hi = f2bf(v);
    unsigned lo = f2bf(v - bf2f(hi));
    int o = mat * 65536 + n * 256 + k;            // transposed
    WtHi[o] = (unsigned short)hi;
    WtLo[o] = (unsigned short)lo;
}

// ---------------------------------------------------------------------------
// Kernel 2: fused QKV projection (3-term bf16 split, fp32 accum). Epilogue
// now emits: Q8hi/Q8lo, K8hi/K8lo (int8 duo, fixed scale 7/127) and
// Vt_perm bf16 [b][d][kv-permuted] (within each 32-kv block, 16B slot s
// holds kv {4s..4s+3, 16+4s..16+4s+3}).
// ---------------------------------------------------------------------------
__global__ __launch_bounds__(256) void proj_kernel(
    const float* __restrict__ x,
    const unsigned short* __restrict__ WtHi, const unsigned short* __restrict__ WtLo,
    const float* __restrict__ bq, const float* __restrict__ bk,
    const float* __restrict__ bv,
    signed char* __restrict__ Q8h, signed char* __restrict__ Q8l,
    signed char* __restrict__ K8h, signed char* __restrict__ K8l,
    unsigned short* __restrict__ Vt)
{
    const int tid = threadIdx.x, lane = tid & 63, wid = tid >> 6;
    const int g = lane >> 4, q16 = lane & 15;
    const int mbase = blockIdx.x * 64 + wid * 16;
    const int nh = blockIdx.y;

    f32x4 acc[3][8];
    #pragma unroll
    for (int m = 0; m < 3; m++)
        #pragma unroll
        for (int n = 0; n < 8; n++) acc[m][n] = f32x4{0.f, 0.f, 0.f, 0.f};

    const float* xr = x + (mbase + q16) * DIM;

    for (int kc = 0; kc < 8; kc++) {
        const float* p = xr + kc * 32 + 8 * g;
        f32x4 va = *(const f32x4*)p;
        f32x4 vb = *(const f32x4*)(p + 4);
        float fv[8] = {va[0], va[1], va[2], va[3], vb[0], vb[1], vb[2], vb[3]};
        unsigned hw[4], lw[4];
        #pragma unroll
        for (int i = 0; i < 4; i++) {
            unsigned h0 = f2bf(fv[2*i]),              h1 = f2bf(fv[2*i+1]);
            unsigned l0 = f2bf(fv[2*i]   - bf2f(h0)), l1 = f2bf(fv[2*i+1] - bf2f(h1));
            hw[i] = h0 | (h1 << 16);
            lw[i] = l0 | (l1 << 16);
        }
        bf16x8 ahi = __builtin_bit_cast(bf16x8, u32x4{hw[0], hw[1], hw[2], hw[3]});
        bf16x8 alo = __builtin_bit_cast(bf16x8, u32x4{lw[0], lw[1], lw[2], lw[3]});

        #pragma unroll
        for (int mat = 0; mat < 3; mat++) {
            #pragma unroll
            for (int nt = 0; nt < 8; nt++) {
                int ncol = nh * 128 + nt * 16 + q16;
                int off  = mat * 65536 + ncol * 256 + kc * 32 + 8 * g;
                bf16x8 bh = *(const bf16x8*)(WtHi + off);
                bf16x8 bl = *(const bf16x8*)(WtLo + off);
                acc[mat][nt] = MFMA(ahi, bh, acc[mat][nt]);
                acc[mat][nt] = MFMA(ahi, bl, acc[mat][nt]);
                acc[mat][nt] = MFMA(alo, bh, acc[mat][nt]);
            }
        }
    }

    #pragma unroll
    for (int nt = 0; nt < 8; nt++) {
        int ncol = nh * 128 + nt * 16 + q16;
        {   // Q -> int8 duo
            float bb = bq[ncol];
            f32x4 c = acc[0][nt];
            #pragma unroll
            for (int r = 0; r < 4; r++) {
                float ys = (c[r] + bb) * QSCALE;
                ys = fminf(fmaxf(ys, -127.f), 127.f);
                float h = rintf(ys);
                float l = rintf((ys - h) * 254.f);
                int mrow = mbase + 4 * g + r;
                Q8h[mrow * DIM + ncol] = (signed char)h;
                Q8l[mrow * DIM + ncol] = (signed char)l;
            }
        }
        {   // K -> int8 duo
            float bb = bk[ncol];
            f32x4 c = acc[1][nt];
            #pragma unroll
            for (int r = 0; r < 4; r++) {
                float ys = (c[r] + bb) * QSCALE;
                ys = fminf(fmaxf(ys, -127.f), 127.f);
                float h = rintf(ys);
                float l = rintf((ys - h) * 254.f);
                int mrow = mbase + 4 * g + r;
                K8h[mrow * DIM + ncol] = (signed char)h;
                K8l[mrow * DIM + ncol] = (signed char)l;
            }
        }
        {   // V -> transposed, column-pair-permuted bf16
            float bb = bv[ncol];
            f32x4 c = acc[2][nt];
            ushort4t pk;
            #pragma unroll
            for (int r = 0; r < 4; r++) pk[r] = (unsigned short)f2bf(c[r] + bb);
            int m0 = mbase + 4 * g;
            int bat = m0 >> 12, s0 = m0 & 4095;
            int w0 = s0 & 31;                       // 4-aligned within 32-block
            int slot = (w0 >> 2) & 3, half = (w0 >> 4) & 1;
            int eo = (s0 & ~31) + slot * 8 + half * 4;
            *(ushort4t*)(Vt + (size_t)(bat * DIM + ncol) * SEQ + eo) = pk;
        }
    }
}

// ---------------------------------------------------------------------------
// Kernel 3: flash attention, int8-duo QK^T + zero-shuffle PV (K=16 bf16).
// 8 waves x 16 q-rows = 128 rows/block; grid (128 qtiles, 2 kv-splits);
// per split 64 chunks of 32 kv. Double-buffered async staging.
// LDS per buffer: K8hi 8KB | K8lo 8KB | V 16KB  -> 64KB total.
// O held col=q (rows=d): rescale/normalize lane-local.
// ---------------------------------------------------------------------------
#define CH_K8H 0
#define CH_K8L 8192
#define CH_V   16384
#define BUFSZ  32768

__global__ __launch_bounds__(512) void flash_kernel(
    const signed char* __restrict__ Q8h, const signed char* __restrict__ Q8l,
    const signed char* __restrict__ K8h, const signed char* __restrict__ K8l,
    const unsigned short* __restrict__ Vt,
    float* __restrict__ o0, unsigned short* __restrict__ o1,
    float2* __restrict__ ml0, float2* __restrict__ ml1)
{
    __shared__ __align__(16) unsigned char smem[65536];

    const int tid = threadIdx.x, lane = tid & 63, wid = tid >> 6;
    const int g = lane >> 4, q16 = lane & 15;
    const int qrow = blockIdx.x * 128 + wid * 16;
    const int b = qrow >> 12;
    const int split = blockIdx.y;
    const int kvbase = split * 2048;
    const int bofs = b * SEQ;
    const int vofs = b * DIM;

    // --- Q8 fragments (B operand: col=q16, k = 64*ks + 16*g + j) ---
    i32x4 qh[4], ql[4];
    {
        const signed char* ph = Q8h + (size_t)(qrow + q16) * DIM + g * 16;
        const signed char* pl = Q8l + (size_t)(qrow + q16) * DIM + g * 16;
        #pragma unroll
        for (int ks = 0; ks < 4; ks++) {
            qh[ks] = *(const i32x4*)(ph + ks * 64);
            ql[ks] = *(const i32x4*)(pl + ks * 64);
        }
    }

    f32x4 o[16];
    #pragma unroll
    for (int i = 0; i < 16; i++) o[i] = f32x4{0.f, 0.f, 0.f, 0.f};
    float m_run = -3.0e38f, l_run = 0.f;

    // ---- staging: 4 x global_load_lds per wave per chunk (32 total) ----
    auto stage = [&](int chunk, int buf) {
        const int kv0 = kvbase + chunk * 32;
        unsigned char* base = smem + buf * BUFSZ;
        {   // K8 hi/lo: wave w covers rows 4w..4w+3 (1KB each)
            const int row = 4 * wid + (lane >> 4);
            const int cs  = (lane & 15) ^ (row & 7);       // src 16B chunk
            const size_t go = (size_t)(bofs + kv0 + row) * DIM + cs * 16;
            gld16(K8h + go, base + CH_K8H + wid * 1024);
            gld16(K8l + go, base + CH_K8L + wid * 1024);
        }
        #pragma unroll
        for (int i = 0; i < 2; i++) {   // V: wave w covers d 32w..32w+31
            const int t = wid * 2 + i;
            const int d = 16 * t + (lane >> 2);
            const int sl = (lane & 3) ^ ((d >> 1) & 3);    // src 16B slot
            gld16(Vt + (size_t)(vofs + d) * SEQ + kv0 + sl * 8,
                  base + CH_V + t * 1024);
        }
    };

    stage(0, 0);
    __syncthreads();

    for (int c = 0; c < 64; c++) {
        const int bf = c & 1;
        if (c + 1 < 64) stage(c + 1, bf ^ 1);

        // ---- QK^T: int8 duo, A=K8 (rows=kv), B=Q8 (cols=q) ----
        const unsigned char* kb = smem + bf * BUFSZ;
        i32x4 T0a{0,0,0,0}, T12a{0,0,0,0}, T0b{0,0,0,0}, T12b{0,0,0,0};
        const int swz = q16 & 7;
        __builtin_amdgcn_s_setprio(1);
        #pragma unroll
        for (int ks = 0; ks < 4; ks++) {
            const int coff = ((4 * ks + g) ^ swz) * 16;
            const unsigned char* ra = kb + CH_K8H + q16 * 256 + coff;
            const unsigned char* rl = kb + CH_K8L + q16 * 256 + coff;
            i32x4 khA = *(const i32x4*)ra;
            i32x4 khB = *(const i32x4*)(ra + 4096);
            i32x4 klA = *(const i32x4*)rl;
            i32x4 klB = *(const i32x4*)(rl + 4096);
            T0a  = MFMA8(khA, qh[ks], T0a);
            T12a = MFMA8(khA, ql[ks], T12a);
            T12a = MFMA8(klA, qh[ks], T12a);
            T0b  = MFMA8(khB, qh[ks], T0b);
            T12b = MFMA8(khB, ql[ks], T12b);
            T12b = MFMA8(klB, qh[ks], T12b);
        }
        __builtin_amdgcn_s_setprio(0);

        // ---- scores (lane holds S[kv=4g+r (+16)][q=q16]) ----
        float s0[4], s1[4];
        #pragma unroll
        for (int r = 0; r < 4; r++) {
            s0[r] = C0 * (float)T0a[r] + C1 * (float)T12a[r];
            s1[r] = C0 * (float)T0b[r] + C1 * (float)T12b[r];
        }

        // ---- online softmax over kv (reduce across lane^16, lane^32) ----
        float pm = fmaxf(fmaxf(fmaxf(s0[0], s0[1]), fmaxf(s0[2], s0[3])),
                         fmaxf(fmaxf(s1[0], s1[1]), fmaxf(s1[2], s1[3])));
        pm = fmaxf(pm, __shfl_xor(pm, 16, 64));
        pm = fmaxf(pm, __shfl_xor(pm, 32, 64));
        float m_new = fmaxf(m_run, pm);
        float e0 = __expf(s0[0] - m_new), e1 = __expf(s0[1] - m_new);
        float e2 = __expf(s0[2] - m_new), e3 = __expf(s0[3] - m_new);
        float e4 = __expf(s1[0] - m_new), e5 = __expf(s1[1] - m_new);
        float e6 = __expf(s1[2] - m_new), e7 = __expf(s1[3] - m_new);
        float psum = ((e0 + e1) + (e2 + e3)) + ((e4 + e5) + (e6 + e7));
        psum += __shfl_xor(psum, 16, 64);
        psum += __shfl_xor(psum, 32, 64);
        float scale = __expf(m_run - m_new);
        l_run = l_run * scale + psum;
        m_run = m_new;

        // ---- P stays in-lane: B fragment for K=16 MFMA is exactly e0..e3 /
        //      e4..e7 (k = 4g+j). Pack to bf16. ----
        short4v p0, p1;
        p0[0] = (short)f2bf(e0); p0[1] = (short)f2bf(e1);
        p0[2] = (short)f2bf(e2); p0[3] = (short)f2bf(e3);
        p1[0] = (short)f2bf(e4); p1[1] = (short)f2bf(e5);
        p1[2] = (short)f2bf(e6); p1[3] = (short)f2bf(e7);

        // ---- PV: A=V^T (rows=d), B=P; O col=q -> lane-local rescale ----
        const unsigned char* vb = kb + CH_V;
        const int vsl = (g ^ ((q16 >> 1) & 3)) * 16;
        __builtin_amdgcn_s_setprio(1);
        #pragma unroll
        for (int dt = 0; dt < 16; dt++) {
            const int d = dt * 16 + q16;
            short8v vf = *(const short8v*)(vb + d * 64 + vsl);
            short4v vlo = {vf[0], vf[1], vf[2], vf[3]};
            short4v vhi = {vf[4], vf[5], vf[6], vf[7]};
            f32x4 oo = o[dt];
            oo[0] *= scale; oo[1] *= scale; oo[2] *= scale; oo[3] *= scale;
            oo = MFMAP(vlo, p0, oo);
            oo = MFMAP(vhi, p1, oo);
            o[dt] = oo;
        }
        __builtin_amdgcn_s_setprio(0);

        __syncthreads();   // drains vmcnt: prefetch landed; buffers reusable
    }

    // ---- epilogue: store UNNORMALIZED partial + (m,l); row=q16, cols=d ----
    if (split == 0) {
        #pragma unroll
        for (int dt = 0; dt < 16; dt++)
            *(f32x4*)(o0 + (size_t)(qrow + q16) * DIM + dt * 16 + 4 * g) = o[dt];
        if (g == 0) ml0[qrow + q16] = float2{m_run, l_run};
    } else {
        #pragma unroll
        for (int dt = 0; dt < 16; dt++) {
            ushort4t pk;
            #pragma unroll
            for (int r = 0; r < 4; r++) pk[r] = (unsigned short)f2bf(o[dt][r]);
            *(ushort4t*)(o1 + (size_t)(qrow + q16) * DIM + dt * 16 + 4 * g) = pk;
        }
        if (g == 0) ml1[qrow + q16] = float2{m_run, l_run};
    }
}

// ---------------------------------------------------------------------------
// Kernel 4: merge the two kv-split partials + residual.
// ---------------------------------------------------------------------------
__global__ __launch_bounds__(256) void combine_kernel(
    const float* __restrict__ o0, const unsigned short* __restrict__ o1,
    const float2* __restrict__ ml0, const float2* __restrict__ ml1,
    const float* __restrict__ x, float* __restrict__ out)
{
    int row = blockIdx.x * 4 + (threadIdx.x >> 6);
    int c0  = (threadIdx.x & 63) * 4;
    float2 A = ml0[row], B = ml1[row];
    float M  = fmaxf(A.x, B.x);
    float w0 = __expf(A.x - M), w1 = __expf(B.x - M);
    float inv = 1.0f / (w0 * A.y + w1 * B.y);
    size_t base = (size_t)row * DIM + c0;
    f32x4    v0 = *(const f32x4*)(o0 + base);
    ushort4t u1 = *(const ushort4t*)(o1 + base);
    f32x4    xr = *(const f32x4*)(x + base);
    f32x4 res;
    #pragma unroll
    for (int j = 0; j < 4; j++)
        res[j] = (w0 * v0[j] + w1 * bf2f((unsigned)u1[j])) * inv + xr[j];
    *(f32x4*)(out + base) = res;
}

// ---------------------------------------------------------------------------
extern "C" void kernel_launch(void* const* d_in, const int* in_sizes, int n_in,
                              void* d_out, int out_size, void* d_ws, size_t ws_size,
                              hipStream_t stream)
{
    const float* x  = (const float*)d_in[0];
    const float* Wq = (const float*)d_in[1];
    const float* bq = (const float*)d_in[2];
    const float* Wk = (const float*)d_in[3];
    const float* bk = (const float*)d_in[4];
    const float* Wv = (const float*)d_in[5];
    const float* bv = (const float*)d_in[6];
    float* out = (float*)d_out;

    unsigned char* ws = (unsigned char*)d_ws;
    signed char*    Q8h  = (signed char*)(ws);
    signed char*    Q8l  = (signed char*)(ws +  4194304);
    signed char*    K8h  = (signed char*)(ws +  8388608);
    signed char*    K8l  = (signed char*)(ws + 12582912);
    unsigned short* Vt   = (unsigned short*)(ws + 16777216);
    unsigned short* WtHi = (unsigned short*)(ws + 25165824);
    unsigned short* WtLo = (unsigned short*)(ws + 25559040);
    unsigned short* O1   = (unsigned short*)(ws + 25952256);
    float2*         ML0  = (float2*)       (ws + 34340864);
    float2*         ML1  = (float2*)       (ws + 34471936);
    // total ws use: 34,603,008 bytes

    convert_w_kernel<<<dim3(256, 3), 256, 0, stream>>>(Wq, Wk, Wv, WtHi, WtLo);
    proj_kernel<<<dim3(256, 2), 256, 0, stream>>>(x, WtHi, WtLo, bq, bk, bv,
                                                  Q8h, Q8l, K8h, K8l, Vt);
    flash_kernel<<<dim3(128, 2), 512, 0, stream>>>(Q8h, Q8l, K8h, K8l, Vt,
                                                   out, O1, ML0, ML1);
    combine_kernel<<<4096, 256, 0, stream>>>(out, O1, ML0, ML1, x, out);
}